// Round 1
// baseline (1802.213 us; speedup 1.0000x reference)
//
#include <hip/hip_runtime.h>

#define D 256
#define KCODES 8192
#define NROWS 32768

// main kernel tiling
#define BN 64
#define BK 256
#define DCH 32

// d_out layout (floats): quantized[8388608] | indices[32768] | commit | codebook | total
#define OUT_Q 0
#define OUT_IDX 8388608
#define OUT_LOSS (8388608 + 32768)

// ws layout (floats): xsq[32768] | esq[8192] | loss[1]
#define WS_XSQ 0
#define WS_ESQ 32768
#define WS_LOSS (32768 + 8192)

// Replicates numpy pairwise_sum semantics for n=256 contiguous f32:
// pairwise(256) = pw128(a) + pw128(a+128); pw128 = 8-accumulator unrolled loop
// then ((r0+r1)+(r2+r3))+((r4+r5)+(r6+r7)). Element = x*x rounded separately
// (no FMA contraction -> use __fmul_rn/__fadd_rn).
__global__ __launch_bounds__(256) void rowsq_kernel(
    const float* __restrict__ src, float* __restrict__ dst, int nrows,
    float* loss_zero) {
  if (loss_zero && blockIdx.x == 0 && threadIdx.x == 0) *loss_zero = 0.0f;
  int r = blockIdx.x * 256 + threadIdx.x;
  if (r >= nrows) return;
  const float4* p4 = (const float4*)(src + (size_t)r * D);
  float total = 0.0f;
  #pragma unroll
  for (int half = 0; half < 2; ++half) {
    float r8[8];
    float4 v0 = p4[half * 32 + 0];
    float4 v1 = p4[half * 32 + 1];
    r8[0] = __fmul_rn(v0.x, v0.x); r8[1] = __fmul_rn(v0.y, v0.y);
    r8[2] = __fmul_rn(v0.z, v0.z); r8[3] = __fmul_rn(v0.w, v0.w);
    r8[4] = __fmul_rn(v1.x, v1.x); r8[5] = __fmul_rn(v1.y, v1.y);
    r8[6] = __fmul_rn(v1.z, v1.z); r8[7] = __fmul_rn(v1.w, v1.w);
    #pragma unroll
    for (int i8 = 1; i8 < 16; ++i8) {
      v0 = p4[half * 32 + i8 * 2];
      v1 = p4[half * 32 + i8 * 2 + 1];
      r8[0] = __fadd_rn(r8[0], __fmul_rn(v0.x, v0.x));
      r8[1] = __fadd_rn(r8[1], __fmul_rn(v0.y, v0.y));
      r8[2] = __fadd_rn(r8[2], __fmul_rn(v0.z, v0.z));
      r8[3] = __fadd_rn(r8[3], __fmul_rn(v0.w, v0.w));
      r8[4] = __fadd_rn(r8[4], __fmul_rn(v1.x, v1.x));
      r8[5] = __fadd_rn(r8[5], __fmul_rn(v1.y, v1.y));
      r8[6] = __fadd_rn(r8[6], __fmul_rn(v1.z, v1.z));
      r8[7] = __fadd_rn(r8[7], __fmul_rn(v1.w, v1.w));
    }
    float s = __fadd_rn(__fadd_rn(__fadd_rn(r8[0], r8[1]), __fadd_rn(r8[2], r8[3])),
                        __fadd_rn(__fadd_rn(r8[4], r8[5]), __fadd_rn(r8[6], r8[7])));
    total = (half == 0) ? s : __fadd_rn(total, s);
  }
  dst[r] = total;
}

// Tiled dot + argmin. Block: 256 threads, 64 rows x all 8192 codes.
// tc = tid&31 (col group, 8 cols each), tr = tid>>5 (row group, 8 rows each).
// LDS: A[d][row] (broadcast reads), B[d][col] (2-way-ish b128 reads).
// Score replicates np f32: s = round(round(xsq - 2*dot) + esq); argmin with
// first-index tie-break via u64 key (score_bits<<32)|idx, score>0 always.
__global__ __launch_bounds__(256, 2) void vq_argmin_kernel(
    const float* __restrict__ x, const float* __restrict__ emb,
    const float* __restrict__ xsq, const float* __restrict__ esq,
    float* __restrict__ out_idx) {
  __shared__ float Alds[DCH][BN];   // 8 KB
  __shared__ float Blds[DCH][BK];   // 32 KB
  const int tid = threadIdx.x;
  const int tc = tid & 31;
  const int tr = tid >> 5;
  const int rowBase = blockIdx.x * BN;

  // staging roles
  const int row_a = tid & 63;        // A: row within tile
  const int dj = (tid >> 6) * 8;     // A: 8-float d-offset within chunk

  float xs[8];
  #pragma unroll
  for (int i = 0; i < 8; ++i) xs[i] = xsq[rowBase + tr * 8 + i];

  unsigned long long best[8];
  #pragma unroll
  for (int i = 0; i < 8; ++i) best[i] = 0xFFFFFFFFFFFFFFFFull;

  for (int kt = 0; kt < KCODES; kt += BK) {
    float acc[8][8];
    #pragma unroll
    for (int i = 0; i < 8; ++i)
      #pragma unroll
      for (int j = 0; j < 8; ++j) acc[i][j] = 0.0f;

    // prologue: load chunk 0 into regs
    float4 aq0, aq1, bq[8];
    {
      const float4* ap = (const float4*)(x + (size_t)(rowBase + row_a) * D + dj);
      aq0 = ap[0]; aq1 = ap[1];
      const float4* bp = (const float4*)(emb + (size_t)(kt + tid) * D);
      #pragma unroll
      for (int jj = 0; jj < 8; ++jj) bq[jj] = bp[jj];
    }

    for (int dc = 0; dc < D / DCH; ++dc) {
      __syncthreads();   // previous chunk's compute done; LDS free
      // transposed stores (conflict-free: lane-consecutive addresses)
      Alds[dj + 0][row_a] = aq0.x; Alds[dj + 1][row_a] = aq0.y;
      Alds[dj + 2][row_a] = aq0.z; Alds[dj + 3][row_a] = aq0.w;
      Alds[dj + 4][row_a] = aq1.x; Alds[dj + 5][row_a] = aq1.y;
      Alds[dj + 6][row_a] = aq1.z; Alds[dj + 7][row_a] = aq1.w;
      #pragma unroll
      for (int jj = 0; jj < 8; ++jj) {
        Blds[jj * 4 + 0][tid] = bq[jj].x;
        Blds[jj * 4 + 1][tid] = bq[jj].y;
        Blds[jj * 4 + 2][tid] = bq[jj].z;
        Blds[jj * 4 + 3][tid] = bq[jj].w;
      }
      __syncthreads();   // LDS ready
      // prefetch next chunk into regs (overlaps with compute below)
      if (dc < D / DCH - 1) {
        const float4* ap = (const float4*)(x + (size_t)(rowBase + row_a) * D + (dc + 1) * DCH + dj);
        aq0 = ap[0]; aq1 = ap[1];
        const float4* bp = (const float4*)(emb + (size_t)(kt + tid) * D + (dc + 1) * DCH);
        #pragma unroll
        for (int jj = 0; jj < 8; ++jj) bq[jj] = bp[jj];
      }
      // 8x8 outer-product accumulate over this d-chunk
      #pragma unroll 8
      for (int d = 0; d < DCH; ++d) {
        const float4 av0 = *(const float4*)(&Alds[d][tr * 8]);
        const float4 av1 = *(const float4*)(&Alds[d][tr * 8 + 4]);
        const float4 bv0 = *(const float4*)(&Blds[d][tc * 8]);
        const float4 bv1 = *(const float4*)(&Blds[d][tc * 8 + 4]);
        const float av[8] = {av0.x, av0.y, av0.z, av0.w, av1.x, av1.y, av1.z, av1.w};
        const float bv[8] = {bv0.x, bv0.y, bv0.z, bv0.w, bv1.x, bv1.y, bv1.z, bv1.w};
        #pragma unroll
        for (int i = 0; i < 8; ++i)
          #pragma unroll
          for (int j = 0; j < 8; ++j)
            acc[i][j] = __builtin_fmaf(av[i], bv[j], acc[i][j]);
      }
    }

    // scoring epilogue for this K-tile (np f32 rounding replicated)
    const float4 e0 = *(const float4*)(esq + kt + tc * 8);
    const float4 e1 = *(const float4*)(esq + kt + tc * 8 + 4);
    const float es[8] = {e0.x, e0.y, e0.z, e0.w, e1.x, e1.y, e1.z, e1.w};
    #pragma unroll
    for (int i = 0; i < 8; ++i) {
      #pragma unroll
      for (int j = 0; j < 8; ++j) {
        float m2 = __fmul_rn(2.0f, acc[i][j]);
        float s1 = __fsub_rn(xs[i], m2);
        float s2 = __fadd_rn(s1, es[j]);
        unsigned long long kk =
            ((unsigned long long)__float_as_uint(s2) << 32) |
            (unsigned)(kt + tc * 8 + j);
        if (kk < best[i]) best[i] = kk;
      }
    }
  }

  // reduce argmin across the 32 col-group lanes (within each 32-lane half)
  #pragma unroll
  for (int i = 0; i < 8; ++i) {
    unsigned long long b = best[i];
    #pragma unroll
    for (int m = 16; m >= 1; m >>= 1) {
      unsigned long long o = __shfl_xor(b, m, 64);
      if (o < b) b = o;
    }
    if (tc == 0) {
      int row = rowBase + tr * 8 + i;
      out_idx[row] = (float)(unsigned)(b & 0xFFFFFFFFull);
    }
  }
}

// Gather quantized rows + accumulate sum((x-q)^2) into loss accumulator.
__global__ __launch_bounds__(256) void gather_kernel(
    const float* __restrict__ x, const float* __restrict__ emb,
    const float* __restrict__ idxf, float* __restrict__ outq,
    float* __restrict__ loss) {
  const int t = threadIdx.x;
  const int row = blockIdx.x * 64 + (t >> 2);
  const int d0 = (t & 3) * 64;
  const int idx = (int)idxf[row];
  const float4* q4 = (const float4*)(emb + (size_t)idx * D + d0);
  const float4* x4 = (const float4*)(x + (size_t)row * D + d0);
  float4* o4 = (float4*)(outq + (size_t)row * D + d0);
  float s = 0.0f;
  #pragma unroll
  for (int j = 0; j < 16; ++j) {
    float4 q = q4[j];
    float4 xv = x4[j];
    o4[j] = q;
    float e0 = xv.x - q.x; s = __builtin_fmaf(e0, e0, s);
    float e1 = xv.y - q.y; s = __builtin_fmaf(e1, e1, s);
    float e2 = xv.z - q.z; s = __builtin_fmaf(e2, e2, s);
    float e3 = xv.w - q.w; s = __builtin_fmaf(e3, e3, s);
  }
  #pragma unroll
  for (int m = 32; m >= 1; m >>= 1) s += __shfl_xor(s, m, 64);
  __shared__ float wsum[4];
  if ((t & 63) == 0) wsum[t >> 6] = s;
  __syncthreads();
  if (t == 0) atomicAdd(loss, ((wsum[0] + wsum[1]) + (wsum[2] + wsum[3])));
}

__global__ void finalize_kernel(const float* __restrict__ loss,
                                float* __restrict__ out3) {
  if (threadIdx.x == 0 && blockIdx.x == 0) {
    float mean = *loss / 8388608.0f;   // exact: /2^23
    float commit = __fmul_rn(0.25f, mean);
    out3[0] = commit;
    out3[1] = mean;
    out3[2] = __fadd_rn(commit, mean);
  }
}

extern "C" void kernel_launch(void* const* d_in, const int* in_sizes, int n_in,
                              void* d_out, int out_size, void* d_ws, size_t ws_size,
                              hipStream_t stream) {
  const float* x = (const float*)d_in[0];    // [32768, 256]
  const float* emb = (const float*)d_in[1];  // [8192, 256]
  float* out = (float*)d_out;
  float* ws = (float*)d_ws;

  float* xsq = ws + WS_XSQ;
  float* esq = ws + WS_ESQ;
  float* lossacc = ws + WS_LOSS;

  rowsq_kernel<<<NROWS / 256, 256, 0, stream>>>(x, xsq, NROWS, nullptr);
  rowsq_kernel<<<KCODES / 256, 256, 0, stream>>>(emb, esq, KCODES, lossacc);
  vq_argmin_kernel<<<NROWS / BN, 256, 0, stream>>>(x, emb, xsq, esq, out + OUT_IDX);
  gather_kernel<<<NROWS / 64, 256, 0, stream>>>(x, emb, out + OUT_IDX, out + OUT_Q, lossacc);
  finalize_kernel<<<1, 64, 0, stream>>>(lossacc, out + OUT_LOSS);
}